// Round 15
// baseline (529.759 us; speedup 1.0000x reference)
//
#include <hip/hip_runtime.h>
#include <hip/hip_bf16.h>
#include <hip/hip_cooperative_groups.h>

#define NODES 100000
#define EDGES 1600000
#define NGRAPH 512
#define BINROWS 512  // rows per bin
#define NBINS 196    // ceil(NODES / 512)
#define CHUNK 4096   // edges per chunk-block
#define NCHUNKS ((EDGES + CHUNK - 1) / CHUNK)
#define VSS 72       // LDS row stride in shorts (144 B, 16B-aligned for b128)

namespace cg = cooperative_groups;

using bf16 = __hip_bfloat16;
typedef long long ll;
using frag8 = __attribute__((ext_vector_type(8))) short;  // 8 bf16 (4 VGPRs)
using f32x4 = __attribute__((ext_vector_type(4))) float;

__device__ __forceinline__ float lrelu(float v) { return v > 0.0f ? v : 0.2f * v; }

__device__ __forceinline__ unsigned mapf(float f) {
    unsigned u = __float_as_uint(f);
    return (u & 0x80000000u) ? ~u : (u | 0x80000000u);
}
__device__ __forceinline__ float unmapf(unsigned u) {
    return __uint_as_float((u & 0x80000000u) ? (u ^ 0x80000000u) : ~u);
}

__device__ __forceinline__ int idx_at(const void* raw, int i, int f) {
    return f ? (int)((const ll*)raw)[i] : ((const int*)raw)[i];
}

__device__ __forceinline__ unsigned short tobf(float f) {
    bf16 h = __float2bfloat16(f);
    return *reinterpret_cast<unsigned short*>(&h);
}

__global__ void sentinel_kernel(float* out, float v) {
    int i = blockIdx.x * blockDim.x + threadIdx.x;
    if (i < NGRAPH * 10) out[i] = v;
}

// Cooperative mega-kernel: init + binCount + scan + binPlace + csr_finalize +
// prescale, with grid.sync() between phases. Exactly NCHUNKS blocks of 256.
// LDS is one raw buffer aliased per phase (23632 B -> 6 blocks/CU capacity,
// far above the 391/256 co-residency requirement).
__global__ void __launch_bounds__(256, 1)
build_csr(const int* __restrict__ eiw, const float* __restrict__ x, int* flag,
          int* binTotal, int* binCursor, int* binStart, int* row_ptr,
          float* dinv1, float* dinv2, int* csr_src, unsigned* staging,
          bf16* xs, unsigned* pooled) {
    cg::grid_group grid = cg::this_grid();
    __shared__ __align__(16) unsigned char smraw[23632];
    int t = threadIdx.x, b = blockIdx.x;
    int gid = b * 256 + t, gstride = gridDim.x * 256;

    // ---- phase 0: init (pooled sentinel = 0 < mapf(any float); counters = 0)
    for (int i = gid; i < NGRAPH * 64; i += gstride) pooled[i] = 0u;
    for (int i = gid; i < 2 * NBINS; i += gstride) binTotal[i] = 0;  // +binCursor
    if (b == 0) {  // int64-storage detect
        int* red = (int*)smraw;
        int v = 0;
        for (int k = t; k < 4096; k += 256) v |= eiw[2 * k + 1];
        for (int o = 32; o; o >>= 1) v |= __shfl_xor(v, o);
        if ((t & 63) == 0) red[t >> 6] = v;
        __syncthreads();
        if (t == 0) flag[0] = ((red[0] | red[1] | red[2] | red[3]) == 0) ? 1 : 0;
    }
    grid.sync();
    int f = flag[0];
    const void* ei = (const void*)eiw;
    int e0 = b * CHUNK;

    // ---- phase 1: per-chunk histogram (kept in LDS across syncs) + binTotal
    int* hist = (int*)(smraw + 20480);
    if (t < NBINS) hist[t] = 0;
    __syncthreads();
#pragma unroll
    for (int k = 0; k < CHUNK / 256; ++k) {
        int i = e0 + k * 256 + t;
        if (i < EDGES) {
            int s = idx_at(ei, i, f), d = idx_at(ei, EDGES + i, f);
            if ((unsigned)s < NODES && (unsigned)d < NODES) atomicAdd(&hist[d >> 9], 1);
        }
    }
    __syncthreads();
    if (t < NBINS && hist[t] > 0) atomicAdd(&binTotal[t], hist[t]);
    grid.sync();

    // ---- phase 2: 196-bin exclusive scan (block 0; uses smraw[0..1024))
    if (b == 0) {
        int* sc = (int*)smraw;
        int v = (t < NBINS) ? binTotal[t] : 0;
        sc[t] = v;
        __syncthreads();
        for (int o = 1; o < 256; o <<= 1) {
            int u = (t >= o) ? sc[t - o] : 0;
            __syncthreads();
            sc[t] += u;
            __syncthreads();
        }
        if (t < NBINS) binStart[t] = sc[t] - v;
        if (t == NBINS - 1) {
            binStart[NBINS] = sc[t];
            row_ptr[NODES] = sc[t];
        }
    }
    grid.sync();

    // ---- phase 3: binPlace. record = (src << 9) | (dst & 511)
    {
        unsigned* recs = (unsigned*)smraw;           // 16384 B
        unsigned char* binsA = smraw + 16384;        // 4096 B
        int* lstart = (int*)(smraw + 21264);         // (NBINS+1)*4
        int* baseg = (int*)(smraw + 22052);          // NBINS*4
        int* lcur = (int*)(smraw + 22836);           // NBINS*4
        if (t < NBINS) lcur[t] = 0;
        __syncthreads();
        if (t == 0) {
            int acc = 0;
            for (int bb = 0; bb < NBINS; ++bb) {
                lstart[bb] = acc;
                acc += hist[bb];
            }
            lstart[NBINS] = acc;
        }
        __syncthreads();
        if (t < NBINS && hist[t] > 0) baseg[t] = atomicAdd(&binCursor[t], hist[t]);
        __syncthreads();
#pragma unroll
        for (int k = 0; k < CHUNK / 256; ++k) {
            int i = e0 + k * 256 + t;
            if (i < EDGES) {
                int s = idx_at(ei, i, f), d = idx_at(ei, EDGES + i, f);
                if ((unsigned)s < NODES && (unsigned)d < NODES) {
                    int bb = d >> 9;
                    int p = lstart[bb] + atomicAdd(&lcur[bb], 1);
                    recs[p] = ((unsigned)s << 9) | (unsigned)(d & 511);
                    binsA[p] = (unsigned char)bb;
                }
            }
        }
        __syncthreads();
        int nv = lstart[NBINS];
        for (int p = t; p < nv; p += 256) {
            int bb = binsA[p];
            staging[binStart[bb] + baseg[bb] + (p - lstart[bb])] = recs[p];
        }
    }
    grid.sync();

    // ---- phase 4: csr_finalize (blocks 0..NBINS-1)
    if (b < NBINS) {
        int* lhist = (int*)smraw;             // 512*4
        int* sc4 = (int*)(smraw + 2048);      // 256*4
        int r0 = b << 9;
        int s0 = binStart[b], s1 = binStart[b + 1];
        for (int j = t; j < BINROWS; j += 256) lhist[j] = 0;
        __syncthreads();
        for (int p = s0 + t; p < s1; p += 256) atomicAdd(&lhist[staging[p] & 511], 1);
        __syncthreads();
        int base = t * 2;
        int v0 = lhist[base], v1 = lhist[base + 1];
        int tsum = v0 + v1;
        sc4[t] = tsum;
        __syncthreads();
        for (int o = 1; o < 256; o <<= 1) {
            int u = (t >= o) ? sc4[t - o] : 0;
            __syncthreads();
            sc4[t] += u;
            __syncthreads();
        }
        int excl = sc4[t] - tsum;
        int ex0 = excl, ex1 = excl + v0;
#pragma unroll
        for (int k = 0; k < 2; ++k) {
            int row = r0 + base + k;
            int ex = k ? ex1 : ex0;
            int dgz = k ? v1 : v0;
            if (row < NODES) {
                row_ptr[row] = s0 + ex;
                float dg = (float)dgz;
                dinv1[row] = 1.0f / sqrtf(dg + 2.0f);
                dinv2[row] = 1.0f / sqrtf(dg + 1.0f);
            }
        }
        __syncthreads();
        lhist[base] = ex0;
        lhist[base + 1] = ex1;
        __syncthreads();
        for (int p = s0 + t; p < s1; p += 256) {
            unsigned rec = staging[p];
            int slot = atomicAdd(&lhist[rec & 511], 1);
            csr_src[s0 + slot] = (int)(rec >> 9);
        }
    }
    grid.sync();

    // ---- phase 5: prescale xs = bf16(x * dinv1), vectorized (float4 -> uint2)
    for (int i = gid; i < NODES * 16; i += gstride) {
        int row = i >> 4;
        float4 xv = ((const float4*)x)[i];
        float d1 = dinv1[row];
        uint2 p;
        p.x = (unsigned)tobf(xv.x * d1) | ((unsigned)tobf(xv.y * d1) << 16);
        p.y = (unsigned)tobf(xv.z * d1) | ((unsigned)tobf(xv.w * d1) << 16);
        ((uint2*)xs)[i] = p;
    }
}

// dual-row quad-edge gather: two independent chains (rows A,B) interleaved for MLP.
// q=lane>>4 covers edge j+q; c=lane&15 covers 8 B (4 bf16 cols). All scalar state.
__device__ __forceinline__ void gather_quad2(
    const uint2* __restrict__ feat4, const int* __restrict__ csr, int begA, int endA,
    int begB, int endB, int lane, float& oxA, float& oyA, float& ozA, float& owA,
    float& oxB, float& oyB, float& ozB, float& owB) {
    int q = lane >> 4, c = lane & 15;
    float a1x = 0, a1y = 0, a1z = 0, a1w = 0, a2x = 0, a2y = 0, a2z = 0, a2w = 0;
    float b1x = 0, b1y = 0, b1z = 0, b1w = 0, b2x = 0, b2y = 0, b2z = 0, b2w = 0;
    int cbA = begA, cbB = begB;
    while (cbA < endA || cbB < endB) {
        int cntA = endA - cbA;
        cntA = cntA > 64 ? 64 : (cntA < 0 ? 0 : cntA);
        int cntB = endB - cbB;
        cntB = cntB > 64 ? 64 : (cntB < 0 ? 0 : cntB);
        int idxA = (lane < cntA) ? csr[cbA + lane] : 0;
        int idxB = (lane < cntB) ? csr[cbB + lane] : 0;
        int jm = cntA > cntB ? cntA : cntB;
        for (int j = 0; j < jm; j += 8) {
            int e0 = j + q, e1 = j + 4 + q;
            if (j < cntA) {
                int sA0 = __shfl(idxA, e0);
                uint2 uA0 = feat4[(size_t)sA0 * 16 + c];
                if (e0 < cntA) {
                    a1x += __uint_as_float(uA0.x << 16);
                    a1y += __uint_as_float(uA0.x & 0xffff0000u);
                    a1z += __uint_as_float(uA0.y << 16);
                    a1w += __uint_as_float(uA0.y & 0xffff0000u);
                }
                if (j + 4 < cntA) {
                    int sA1 = __shfl(idxA, e1);
                    uint2 uA1 = feat4[(size_t)sA1 * 16 + c];
                    if (e1 < cntA) {
                        a2x += __uint_as_float(uA1.x << 16);
                        a2y += __uint_as_float(uA1.x & 0xffff0000u);
                        a2z += __uint_as_float(uA1.y << 16);
                        a2w += __uint_as_float(uA1.y & 0xffff0000u);
                    }
                }
            }
            if (j < cntB) {
                int sB0 = __shfl(idxB, e0);
                uint2 uB0 = feat4[(size_t)sB0 * 16 + c];
                if (e0 < cntB) {
                    b1x += __uint_as_float(uB0.x << 16);
                    b1y += __uint_as_float(uB0.x & 0xffff0000u);
                    b1z += __uint_as_float(uB0.y << 16);
                    b1w += __uint_as_float(uB0.y & 0xffff0000u);
                }
                if (j + 4 < cntB) {
                    int sB1 = __shfl(idxB, e1);
                    uint2 uB1 = feat4[(size_t)sB1 * 16 + c];
                    if (e1 < cntB) {
                        b2x += __uint_as_float(uB1.x << 16);
                        b2y += __uint_as_float(uB1.x & 0xffff0000u);
                        b2z += __uint_as_float(uB1.y << 16);
                        b2w += __uint_as_float(uB1.y & 0xffff0000u);
                    }
                }
            }
        }
        cbA += 64;
        cbB += 64;
    }
    a1x += a2x; a1y += a2y; a1z += a2z; a1w += a2w;
    b1x += b2x; b1y += b2y; b1z += b2z; b1w += b2w;
    a1x += __shfl_xor(a1x, 16); a1y += __shfl_xor(a1y, 16);
    a1z += __shfl_xor(a1z, 16); a1w += __shfl_xor(a1w, 16);
    b1x += __shfl_xor(b1x, 16); b1y += __shfl_xor(b1y, 16);
    b1z += __shfl_xor(b1z, 16); b1w += __shfl_xor(b1w, 16);
    a1x += __shfl_xor(a1x, 32); a1y += __shfl_xor(a1y, 32);
    a1z += __shfl_xor(a1z, 32); a1w += __shfl_xor(a1w, 32);
    b1x += __shfl_xor(b1x, 32); b1y += __shfl_xor(b1y, 32);
    b1z += __shfl_xor(b1z, 32); b1w += __shfl_xor(b1w, 32);
    oxA = a1x; oyA = a1y; ozA = a1z; owA = a1w;
    oxB = b1x; oyB = b1y; ozB = b1z; owB = b1w;
}

// shared body: stage W^T, gather 16 rows/wave (2 chains at a time) into Vs, MFMA.
// acc[nt] C/D layout: col=lane&15, row=quad*4+reg (verified).
__device__ __forceinline__ void gcn_core(const uint2* __restrict__ feat4,
                                         const int* __restrict__ csr,
                                         const int* __restrict__ rp,
                                         const float* __restrict__ dinv, float selfw,
                                         const float* __restrict__ W, short* Vs, short* Wt,
                                         int rowBase, int lane, int wave, f32x4 (&acc)[4]) {
    int t = wave * 64 + lane;
    for (int i = t; i < 4096; i += 256) {  // Wt[n][k] = W[k][n], bf16
        int k = i >> 6, n = i & 63;
        Wt[n * VSS + k] = (short)tobf(W[i]);
    }
    __syncthreads();
    int myBase = rowBase + wave * 16;
    int rpv = (lane < 17) ? rp[min(myBase + lane, NODES)] : 0;
    int c = lane & 15;
    for (int ii = 0; ii < 8; ++ii) {
        int iA = ii, iB = ii + 8;
        int begA = __shfl(rpv, iA), endA = __shfl(rpv, iA + 1);
        int begB = __shfl(rpv, iB), endB = __shfl(rpv, iB + 1);
        float vxA, vyA, vzA, vwA, vxB, vyB, vzB, vwB;
        gather_quad2(feat4, csr, begA, endA, begB, endB, lane, vxA, vyA, vzA, vwA, vxB,
                     vyB, vzB, vwB);
        int rowA = myBase + iA, rowB = myBase + iB;
        float dvA = 0.0f, dvB = 0.0f;
        uint2 usA = make_uint2(0u, 0u), usB = make_uint2(0u, 0u);
        if (rowA < NODES) {
            dvA = dinv[rowA];
            usA = feat4[(size_t)rowA * 16 + c];
        }
        if (rowB < NODES) {
            dvB = dinv[rowB];
            usB = feat4[(size_t)rowB * 16 + c];
        }
        vxA = dvA * (vxA + selfw * __uint_as_float(usA.x << 16));
        vyA = dvA * (vyA + selfw * __uint_as_float(usA.x & 0xffff0000u));
        vzA = dvA * (vzA + selfw * __uint_as_float(usA.y << 16));
        vwA = dvA * (vwA + selfw * __uint_as_float(usA.y & 0xffff0000u));
        vxB = dvB * (vxB + selfw * __uint_as_float(usB.x << 16));
        vyB = dvB * (vyB + selfw * __uint_as_float(usB.x & 0xffff0000u));
        vzB = dvB * (vzB + selfw * __uint_as_float(usB.y << 16));
        vwB = dvB * (vwB + selfw * __uint_as_float(usB.y & 0xffff0000u));
        if (lane < 16) {
            uint2 pA, pB;
            pA.x = (unsigned)tobf(vxA) | ((unsigned)tobf(vyA) << 16);
            pA.y = (unsigned)tobf(vzA) | ((unsigned)tobf(vwA) << 16);
            pB.x = (unsigned)tobf(vxB) | ((unsigned)tobf(vyB) << 16);
            pB.y = (unsigned)tobf(vzB) | ((unsigned)tobf(vwB) << 16);
            *(uint2*)(Vs + (size_t)(wave * 16 + iA) * VSS + c * 4) = pA;
            *(uint2*)(Vs + (size_t)(wave * 16 + iB) * VSS + c * 4) = pB;
        }
    }
    frag8 afr[2];
    int m = lane & 15, q = lane >> 4;
#pragma unroll
    for (int ks = 0; ks < 2; ++ks)
        afr[ks] = *(frag8*)(Vs + (size_t)(wave * 16 + m) * VSS + q * 8 + ks * 32);
#pragma unroll
    for (int nt = 0; nt < 4; ++nt) {
        f32x4 a = {0.f, 0.f, 0.f, 0.f};
#pragma unroll
        for (int ks = 0; ks < 2; ++ks) {
            frag8 bfr = *(frag8*)(Wt + (size_t)(nt * 16 + m) * VSS + q * 8 + ks * 32);
            a = __builtin_amdgcn_mfma_f32_16x16x32_bf16(afr[ks], bfr, a, 0, 0, 0);
        }
        acc[nt] = a;
    }
}

// layer1: gather + MFMA + bias + LN + leaky -> h1s = h1*dinv2 (bf16)
__global__ void __launch_bounds__(256, 2)
gcn1_fused(const uint2* __restrict__ xs4, const int* __restrict__ csr,
           const int* __restrict__ rp, const float* __restrict__ dinv1,
           const float* __restrict__ dinv2, const float* __restrict__ W1,
           const float* __restrict__ b1, const float* __restrict__ lng,
           const float* __restrict__ lnb, bf16* __restrict__ h1s) {
    __shared__ short sm[2 * 64 * VSS];
    short* Vs = sm;
    short* Wt = sm + 64 * VSS;
    int lane = threadIdx.x & 63, wave = threadIdx.x >> 6;
    int rowBase = blockIdx.x * 64;
    f32x4 acc[4];
    gcn_core(xs4, csr, rp, dinv1, 2.0f, W1, Vs, Wt, rowBase, lane, wave, acc);
    int c = lane & 15, q = lane >> 4;
    float bc[4], lg[4], lb[4];
#pragma unroll
    for (int nt = 0; nt < 4; ++nt) {
        bc[nt] = b1[nt * 16 + c];
        lg[nt] = lng[nt * 16 + c];
        lb[nt] = lnb[nt * 16 + c];
    }
#pragma unroll
    for (int r = 0; r < 4; ++r) {
        int grow = rowBase + wave * 16 + q * 4 + r;
        float v0 = acc[0][r] + bc[0], v1 = acc[1][r] + bc[1];
        float v2 = acc[2][r] + bc[2], v3 = acc[3][r] + bc[3];
        float s = v0 + v1 + v2 + v3;
        for (int o = 1; o < 16; o <<= 1) s += __shfl_xor(s, o);
        float mu = s * (1.0f / 64.0f);
        float d0 = v0 - mu, d1 = v1 - mu, d2 = v2 - mu, d3 = v3 - mu;
        float qq = d0 * d0 + d1 * d1 + d2 * d2 + d3 * d3;
        for (int o = 1; o < 16; o <<= 1) qq += __shfl_xor(qq, o);
        float rstd = 1.0f / sqrtf(qq * (1.0f / 64.0f) + 1e-5f);
        if (grow < NODES) {
            float d2v = dinv2[grow];
            bf16* dst = h1s + (size_t)grow * 64 + c;
            dst[0]  = __float2bfloat16(lrelu(d0 * rstd * lg[0] + lb[0]) * d2v);
            dst[16] = __float2bfloat16(lrelu(d1 * rstd * lg[1] + lb[1]) * d2v);
            dst[32] = __float2bfloat16(lrelu(d2 * rstd * lg[2] + lb[2]) * d2v);
            dst[48] = __float2bfloat16(lrelu(d3 * rstd * lg[3] + lb[3]) * d2v);
        }
    }
}

// layer2: gather + MFMA + bias + leaky + run-merged max-pool
__global__ void __launch_bounds__(256, 2)
gcn2_fused(const uint2* __restrict__ h1s4, const int* __restrict__ csr,
           const int* __restrict__ rp, const float* __restrict__ dinv2,
           const float* __restrict__ W2, const float* __restrict__ b2,
           const void* __restrict__ batch, const int* __restrict__ flag,
           unsigned* __restrict__ pooled) {
    __shared__ short sm[2 * 64 * VSS];
    __shared__ int gsh[64];
    short* Vs = sm;
    short* Wt = sm + 64 * VSS;
    int t = threadIdx.x, lane = t & 63, wave = t >> 6;
    int rowBase = blockIdx.x * 64;
    if (t < 64) {
        int row = rowBase + t;
        gsh[t] = (row < NODES) ? idx_at(batch, row, flag[0]) : -1;
    }
    f32x4 acc[4];
    gcn_core(h1s4, csr, rp, dinv2, 1.0f, W2, Vs, Wt, rowBase, lane, wave, acc);
    int c = lane & 15, q = lane >> 4;
    float bc[4];
#pragma unroll
    for (int nt = 0; nt < 4; ++nt) bc[nt] = b2[nt * 16 + c];
    __syncthreads();
    float* P = (float*)sm;  // 64 x 65 fp32 pool buffer
#pragma unroll
    for (int r = 0; r < 4; ++r) {
        int mloc = wave * 16 + q * 4 + r;
#pragma unroll
        for (int nt = 0; nt < 4; ++nt)
            P[(size_t)mloc * 65 + nt * 16 + c] = lrelu(acc[nt][r] + bc[nt]);
    }
    __syncthreads();
    if (wave == 0) {
        float m = P[lane];
        int gc = gsh[0];
        for (int r = 1; r < 64; ++r) {
            int gr = gsh[r];
            float ar = P[(size_t)r * 65 + lane];
            if (gr == gc) {
                m = fmaxf(m, ar);
            } else {
                if ((unsigned)gc < NGRAPH) atomicMax(&pooled[gc * 64 + lane], mapf(m));
                gc = gr;
                m = ar;
            }
        }
        if ((unsigned)gc < NGRAPH) atomicMax(&pooled[gc * 64 + lane], mapf(m));
    }
}

// head: z = pooled@W3+b3; LN; leaky; z@W4+b4; softmax. One block per graph.
__global__ void head_kernel(const unsigned* __restrict__ pooled, const float* __restrict__ W3,
                            const float* __restrict__ b3, const float* __restrict__ g2,
                            const float* __restrict__ be2, const float* __restrict__ W4,
                            const float* __restrict__ b4, float* __restrict__ out) {
    __shared__ float prow[64];
    __shared__ float z[768];
    __shared__ float rs[4], rss[4];
    __shared__ float mu_s, rstd_s;
    __shared__ float red[10];
    int t = threadIdx.x, gI = blockIdx.x;
    if (t < 64) prow[t] = unmapf(pooled[gI * 64 + t]);
    __syncthreads();
    for (int c = t; c < 768; c += 256) {
        float acc = b3[c];
#pragma unroll 16
        for (int k = 0; k < 64; ++k) acc += prow[k] * W3[k * 768 + c];
        z[c] = acc;
    }
    __syncthreads();
    float s = 0.0f, ss = 0.0f;
    for (int c = t; c < 768; c += 256) {
        float v = z[c];
        s += v;
        ss += v * v;
    }
    for (int o = 32; o; o >>= 1) {
        s += __shfl_xor(s, o);
        ss += __shfl_xor(ss, o);
    }
    if ((t & 63) == 0) { rs[t >> 6] = s; rss[t >> 6] = ss; }
    __syncthreads();
    if (t == 0) {
        float S = rs[0] + rs[1] + rs[2] + rs[3];
        float SS = rss[0] + rss[1] + rss[2] + rss[3];
        float mu = S * (1.0f / 768.0f);
        float var = SS * (1.0f / 768.0f) - mu * mu;
        mu_s = mu;
        rstd_s = 1.0f / sqrtf(fmaxf(var, 0.0f) + 1e-5f);
    }
    __syncthreads();
    for (int c = t; c < 768; c += 256) {
        float y = (z[c] - mu_s) * rstd_s * g2[c] + be2[c];
        z[c] = lrelu(y);
    }
    if (t < 10) red[t] = 0.0f;
    __syncthreads();
    float p[10];
#pragma unroll
    for (int c = 0; c < 10; ++c) p[c] = 0.0f;
    for (int k = t; k < 768; k += 256) {
        float zv = z[k];
#pragma unroll
        for (int c = 0; c < 10; ++c) p[c] += zv * W4[k * 10 + c];
    }
#pragma unroll
    for (int c = 0; c < 10; ++c) atomicAdd(&red[c], p[c]);
    __syncthreads();
    if (t == 0) {
        float l[10], m = -1e30f;
#pragma unroll
        for (int c = 0; c < 10; ++c) {
            l[c] = red[c] + b4[c];
            m = fmaxf(m, l[c]);
        }
        float sum = 0.0f;
#pragma unroll
        for (int c = 0; c < 10; ++c) {
            l[c] = expf(l[c] - m);
            sum += l[c];
        }
        float inv = 1.0f / sum;
#pragma unroll
        for (int c = 0; c < 10; ++c) out[gI * 10 + c] = l[c] * inv;
    }
}

extern "C" void kernel_launch(void* const* d_in, const int* in_sizes, int n_in,
                              void* d_out, int out_size, void* d_ws, size_t ws_size,
                              hipStream_t stream) {
    const size_t REQUIRED = (size_t)NODES * 64 * 2 * 2    // xs + h1s (staging aliases)
                          + (size_t)EDGES * 4             // csr_src
                          + (size_t)(NODES + 1) * 4       // row_ptr
                          + (size_t)NODES * 4 * 2         // dinv1, dinv2
                          + (size_t)(NBINS * 3 + 1) * 4   // binTotal, binCursor, binStart
                          + (size_t)NGRAPH * 64 * 4       // pooled
                          + 16;                           // flag
    if (ws_size < REQUIRED) {
        sentinel_kernel<<<20, 256, 0, stream>>>((float*)d_out, 64.0f);
        return;
    }

    const float* x = (const float*)d_in[0];
    const int* eiw = (const int*)d_in[1];
    const void* batch = d_in[2];
    const float* W1 = (const float*)d_in[3];
    const float* b1 = (const float*)d_in[4];
    const float* lng = (const float*)d_in[5];
    const float* lnb = (const float*)d_in[6];
    const float* W2 = (const float*)d_in[7];
    const float* b2 = (const float*)d_in[8];
    const float* W3 = (const float*)d_in[9];
    const float* b3 = (const float*)d_in[10];
    const float* g2 = (const float*)d_in[11];
    const float* be2 = (const float*)d_in[12];
    const float* W4 = (const float*)d_in[13];
    const float* b4 = (const float*)d_in[14];

    bf16* xs = (bf16*)d_ws;                               // N*64 bf16
    bf16* h1s = xs + (size_t)NODES * 64;                  // N*64 bf16
    unsigned* staging = (unsigned*)h1s;                   // E*4 (aliases h1s; dead by gcn1)
    int* csr_src = (int*)(h1s + (size_t)NODES * 64);      // E
    int* row_ptr = csr_src + EDGES;                       // N+1
    float* dinv1 = (float*)(row_ptr + NODES + 1);         // N
    float* dinv2 = dinv1 + NODES;                         // N
    int* binTotal = (int*)(dinv2 + NODES);                // NBINS
    int* binCursor = binTotal + NBINS;                    // NBINS (contiguous w/ binTotal)
    int* binStart = binCursor + NBINS;                    // NBINS+1
    unsigned* pooled = (unsigned*)(binStart + NBINS + 1); // G*64
    int* flag = (int*)(pooled + NGRAPH * 64);             // 1

    // single cooperative kernel: init + count + scan + place + finalize + prescale
    {
        void* args[] = {(void*)&eiw,     (void*)&x,      (void*)&flag,
                        (void*)&binTotal, (void*)&binCursor, (void*)&binStart,
                        (void*)&row_ptr,  (void*)&dinv1,  (void*)&dinv2,
                        (void*)&csr_src,  (void*)&staging, (void*)&xs,
                        (void*)&pooled};
        hipLaunchCooperativeKernel((void*)build_csr, dim3(NCHUNKS), dim3(256), args, 0,
                                   stream);
    }

    // fused layers: 64 rows/block (4 waves x 16 rows), dual-chain gather + MFMA
    gcn1_fused<<<(NODES + 63) / 64, 256, 0, stream>>>((const uint2*)xs, csr_src, row_ptr,
                                                      dinv1, dinv2, W1, b1, lng, lnb, h1s);
    gcn2_fused<<<(NODES + 63) / 64, 256, 0, stream>>>((const uint2*)h1s, csr_src, row_ptr,
                                                      dinv2, W2, b2, batch, flag, pooled);

    // head
    head_kernel<<<NGRAPH, 256, 0, stream>>>(pooled, W3, b3, g2, be2, W4, b4, (float*)d_out);
}

// Round 16
// 298.410 us; speedup vs baseline: 1.7753x; 1.7753x over previous
//
#include <hip/hip_runtime.h>
#include <hip/hip_bf16.h>

#define NODES 100000
#define EDGES 1600000
#define NGRAPH 512
#define BINROWS 512   // rows per bin
#define NBINS 196     // ceil(NODES / 512)
#define BINCAP 12288  // staging slots per bin (mean 8192, sd ~90 -> 45 sigma margin)
#define CHUNK 4096    // edges per binPlace block
#define NCHUNKS ((EDGES + CHUNK - 1) / CHUNK)
#define VSS 72        // LDS row stride in shorts (144 B, 16B-aligned for b128)

using bf16 = __hip_bfloat16;
typedef long long ll;
using frag8 = __attribute__((ext_vector_type(8))) short;  // 8 bf16 (4 VGPRs)
using f32x4 = __attribute__((ext_vector_type(4))) float;

__device__ __forceinline__ float lrelu(float v) { return v > 0.0f ? v : 0.2f * v; }

__device__ __forceinline__ unsigned mapf(float f) {
    unsigned u = __float_as_uint(f);
    return (u & 0x80000000u) ? ~u : (u | 0x80000000u);
}
__device__ __forceinline__ float unmapf(unsigned u) {
    return __uint_as_float((u & 0x80000000u) ? (u ^ 0x80000000u) : ~u);
}

__device__ __forceinline__ int idx_at(const void* raw, int i, int f) {
    return f ? (int)((const ll*)raw)[i] : ((const int*)raw)[i];
}

__device__ __forceinline__ unsigned short tobf(float f) {
    bf16 h = __float2bfloat16(f);
    return *reinterpret_cast<unsigned short*>(&h);
}

__global__ void sentinel_kernel(float* out, float v) {
    int i = blockIdx.x * blockDim.x + threadIdx.x;
    if (i < NGRAPH * 10) out[i] = v;
}

// single-pass staging build: per-block flag self-detect + local hist + global
// reservation into fixed-capacity bin slots. record = (src << 9) | (dst & 511).
__global__ void binPlace(const int* __restrict__ eiw, int* __restrict__ flag,
                         int* __restrict__ binCursor, unsigned* __restrict__ staging) {
    __shared__ unsigned recs[CHUNK];
    __shared__ unsigned char binsA[CHUNK];
    __shared__ int hist[NBINS], lstart[NBINS + 1], baseg[NBINS], lcur[NBINS];
    __shared__ int red[4];
    int t = threadIdx.x;
    int e0 = blockIdx.x * CHUNK;
    int eEnd = min(e0 + CHUNK, EDGES);
    // self-detect int64 storage from own chunk's odd words (ids<2^17: all-zero
    // iff int64; for int32 these are real node ids -> nonzero w.h.p.)
    int v = 0;
    for (int k = e0 + t; k < eEnd; k += 256) v |= eiw[2 * k + 1];
    for (int o = 32; o; o >>= 1) v |= __shfl_xor(v, o);
    if ((t & 63) == 0) red[t >> 6] = v;
    if (t < NBINS) { hist[t] = 0; lcur[t] = 0; }
    __syncthreads();
    int f = ((red[0] | red[1] | red[2] | red[3]) == 0) ? 1 : 0;
    if (blockIdx.x == 0 && t == 0) flag[0] = f;  // publish for downstream kernels
    const void* ei = (const void*)eiw;
    for (int i = e0 + t; i < eEnd; i += 256) {
        int s = idx_at(ei, i, f), d = idx_at(ei, EDGES + i, f);
        if ((unsigned)s < NODES && (unsigned)d < NODES) atomicAdd(&hist[d >> 9], 1);
    }
    __syncthreads();
    if (t == 0) {
        int acc = 0;
        for (int bb = 0; bb < NBINS; ++bb) {
            lstart[bb] = acc;
            acc += hist[bb];
        }
        lstart[NBINS] = acc;
    }
    __syncthreads();
    if (t < NBINS && hist[t] > 0) baseg[t] = atomicAdd(&binCursor[t], hist[t]);
    __syncthreads();
    for (int i = e0 + t; i < eEnd; i += 256) {
        int s = idx_at(ei, i, f), d = idx_at(ei, EDGES + i, f);
        if ((unsigned)s < NODES && (unsigned)d < NODES) {
            int bb = d >> 9;
            int p = lstart[bb] + atomicAdd(&lcur[bb], 1);
            recs[p] = ((unsigned)s << 9) | (unsigned)(d & 511);
            binsA[p] = (unsigned char)bb;
        }
    }
    __syncthreads();
    int nv = lstart[NBINS];
    for (int p = t; p < nv; p += 256) {
        int bb = binsA[p];
        int idx = baseg[bb] + (p - lstart[bb]);
        if (idx < BINCAP) staging[(size_t)bb * BINCAP + idx] = recs[p];
    }
}

// one block per bin: self-compute global offset (prefix over binCursor), local
// degree hist + scan -> row_ptr/dinv1/dinv2, scatter src into csr_src.
__global__ void csr_finalize(const unsigned* __restrict__ staging,
                             const int* __restrict__ binCursor, int* __restrict__ row_ptr,
                             float* __restrict__ dinv1, float* __restrict__ dinv2,
                             int* __restrict__ csr_src) {
    __shared__ int lhist[BINROWS];
    __shared__ int sc[256];
    __shared__ int startSh;
    int b = blockIdx.x, t = threadIdx.x;
    int cv = (t < NBINS) ? binCursor[t] : 0;
    sc[t] = (t < b) ? cv : 0;  // exclusive prefix mask
    __syncthreads();
    for (int o = 128; o; o >>= 1) {
        if (t < o) sc[t] += sc[t + o];
        __syncthreads();
    }
    if (t == 0) startSh = sc[0];
    __syncthreads();
    int myStart = startSh;
    int cnt = binCursor[b];
    if (b == NBINS - 1 && t == 0) row_ptr[NODES] = myStart + cnt;
    const unsigned* st = staging + (size_t)b * BINCAP;
    int r0 = b << 9;
    for (int j = t; j < BINROWS; j += 256) lhist[j] = 0;
    __syncthreads();
    for (int p = t; p < cnt; p += 256) atomicAdd(&lhist[st[p] & 511], 1);
    __syncthreads();
    int base = t * 2;
    int v0 = lhist[base], v1 = lhist[base + 1];
    int tsum = v0 + v1;
    sc[t] = tsum;
    __syncthreads();
    for (int o = 1; o < 256; o <<= 1) {
        int u = (t >= o) ? sc[t - o] : 0;
        __syncthreads();
        sc[t] += u;
        __syncthreads();
    }
    int excl = sc[t] - tsum;
    int ex0 = excl, ex1 = excl + v0;
#pragma unroll
    for (int k = 0; k < 2; ++k) {
        int row = r0 + base + k;
        int ex = k ? ex1 : ex0;
        int dgz = k ? v1 : v0;
        if (row < NODES) {
            row_ptr[row] = myStart + ex;
            float dg = (float)dgz;
            dinv1[row] = 1.0f / sqrtf(dg + 2.0f);
            dinv2[row] = 1.0f / sqrtf(dg + 1.0f);
        }
    }
    __syncthreads();
    lhist[base] = ex0;
    lhist[base + 1] = ex1;
    __syncthreads();
    for (int p = t; p < cnt; p += 256) {
        unsigned rec = st[p];
        int slot = atomicAdd(&lhist[rec & 511], 1);
        csr_src[myStart + slot] = (int)(rec >> 9);
    }
}

// xs = bf16(x * dinv1), vectorized, saturating grid
__global__ void prescale_x(const float* __restrict__ x, const float* __restrict__ dinv1,
                           bf16* __restrict__ xs) {
    int i = blockIdx.x * blockDim.x + threadIdx.x;
    if (i >= NODES * 16) return;
    int row = i >> 4;
    float4 xv = ((const float4*)x)[i];
    float d1 = dinv1[row];
    uint2 p;
    p.x = (unsigned)tobf(xv.x * d1) | ((unsigned)tobf(xv.y * d1) << 16);
    p.y = (unsigned)tobf(xv.z * d1) | ((unsigned)tobf(xv.w * d1) << 16);
    ((uint2*)xs)[i] = p;
}

// dual-row quad-edge gather: two independent chains (rows A,B) interleaved for MLP.
// q=lane>>4 covers edge j+q; c=lane&15 covers 8 B (4 bf16 cols). All scalar state.
__device__ __forceinline__ void gather_quad2(
    const uint2* __restrict__ feat4, const int* __restrict__ csr, int begA, int endA,
    int begB, int endB, int lane, float& oxA, float& oyA, float& ozA, float& owA,
    float& oxB, float& oyB, float& ozB, float& owB) {
    int q = lane >> 4, c = lane & 15;
    float a1x = 0, a1y = 0, a1z = 0, a1w = 0, a2x = 0, a2y = 0, a2z = 0, a2w = 0;
    float b1x = 0, b1y = 0, b1z = 0, b1w = 0, b2x = 0, b2y = 0, b2z = 0, b2w = 0;
    int cbA = begA, cbB = begB;
    while (cbA < endA || cbB < endB) {
        int cntA = endA - cbA;
        cntA = cntA > 64 ? 64 : (cntA < 0 ? 0 : cntA);
        int cntB = endB - cbB;
        cntB = cntB > 64 ? 64 : (cntB < 0 ? 0 : cntB);
        int idxA = (lane < cntA) ? csr[cbA + lane] : 0;
        int idxB = (lane < cntB) ? csr[cbB + lane] : 0;
        int jm = cntA > cntB ? cntA : cntB;
        for (int j = 0; j < jm; j += 8) {
            int e0 = j + q, e1 = j + 4 + q;
            if (j < cntA) {
                int sA0 = __shfl(idxA, e0);
                uint2 uA0 = feat4[(size_t)sA0 * 16 + c];
                if (e0 < cntA) {
                    a1x += __uint_as_float(uA0.x << 16);
                    a1y += __uint_as_float(uA0.x & 0xffff0000u);
                    a1z += __uint_as_float(uA0.y << 16);
                    a1w += __uint_as_float(uA0.y & 0xffff0000u);
                }
                if (j + 4 < cntA) {
                    int sA1 = __shfl(idxA, e1);
                    uint2 uA1 = feat4[(size_t)sA1 * 16 + c];
                    if (e1 < cntA) {
                        a2x += __uint_as_float(uA1.x << 16);
                        a2y += __uint_as_float(uA1.x & 0xffff0000u);
                        a2z += __uint_as_float(uA1.y << 16);
                        a2w += __uint_as_float(uA1.y & 0xffff0000u);
                    }
                }
            }
            if (j < cntB) {
                int sB0 = __shfl(idxB, e0);
                uint2 uB0 = feat4[(size_t)sB0 * 16 + c];
                if (e0 < cntB) {
                    b1x += __uint_as_float(uB0.x << 16);
                    b1y += __uint_as_float(uB0.x & 0xffff0000u);
                    b1z += __uint_as_float(uB0.y << 16);
                    b1w += __uint_as_float(uB0.y & 0xffff0000u);
                }
                if (j + 4 < cntB) {
                    int sB1 = __shfl(idxB, e1);
                    uint2 uB1 = feat4[(size_t)sB1 * 16 + c];
                    if (e1 < cntB) {
                        b2x += __uint_as_float(uB1.x << 16);
                        b2y += __uint_as_float(uB1.x & 0xffff0000u);
                        b2z += __uint_as_float(uB1.y << 16);
                        b2w += __uint_as_float(uB1.y & 0xffff0000u);
                    }
                }
            }
        }
        cbA += 64;
        cbB += 64;
    }
    a1x += a2x; a1y += a2y; a1z += a2z; a1w += a2w;
    b1x += b2x; b1y += b2y; b1z += b2z; b1w += b2w;
    a1x += __shfl_xor(a1x, 16); a1y += __shfl_xor(a1y, 16);
    a1z += __shfl_xor(a1z, 16); a1w += __shfl_xor(a1w, 16);
    b1x += __shfl_xor(b1x, 16); b1y += __shfl_xor(b1y, 16);
    b1z += __shfl_xor(b1z, 16); b1w += __shfl_xor(b1w, 16);
    a1x += __shfl_xor(a1x, 32); a1y += __shfl_xor(a1y, 32);
    a1z += __shfl_xor(a1z, 32); a1w += __shfl_xor(a1w, 32);
    b1x += __shfl_xor(b1x, 32); b1y += __shfl_xor(b1y, 32);
    b1z += __shfl_xor(b1z, 32); b1w += __shfl_xor(b1w, 32);
    oxA = a1x; oyA = a1y; ozA = a1z; owA = a1w;
    oxB = b1x; oyB = b1y; ozB = b1z; owB = b1w;
}

// shared body: stage W^T, gather 16 rows/wave (2 chains at a time) into Vs, MFMA.
// acc[nt] C/D layout: col=lane&15, row=quad*4+reg (verified).
__device__ __forceinline__ void gcn_core(const uint2* __restrict__ feat4,
                                         const int* __restrict__ csr,
                                         const int* __restrict__ rp,
                                         const float* __restrict__ dinv, float selfw,
                                         const float* __restrict__ W, short* Vs, short* Wt,
                                         int rowBase, int lane, int wave, f32x4 (&acc)[4]) {
    int t = wave * 64 + lane;
    for (int i = t; i < 4096; i += 256) {  // Wt[n][k] = W[k][n], bf16
        int k = i >> 6, n = i & 63;
        Wt[n * VSS + k] = (short)tobf(W[i]);
    }
    __syncthreads();
    int myBase = rowBase + wave * 16;
    int rpv = (lane < 17) ? rp[min(myBase + lane, NODES)] : 0;
    int c = lane & 15;
    for (int ii = 0; ii < 8; ++ii) {
        int iA = ii, iB = ii + 8;
        int begA = __shfl(rpv, iA), endA = __shfl(rpv, iA + 1);
        int begB = __shfl(rpv, iB), endB = __shfl(rpv, iB + 1);
        float vxA, vyA, vzA, vwA, vxB, vyB, vzB, vwB;
        gather_quad2(feat4, csr, begA, endA, begB, endB, lane, vxA, vyA, vzA, vwA, vxB,
                     vyB, vzB, vwB);
        int rowA = myBase + iA, rowB = myBase + iB;
        float dvA = 0.0f, dvB = 0.0f;
        uint2 usA = make_uint2(0u, 0u), usB = make_uint2(0u, 0u);
        if (rowA < NODES) {
            dvA = dinv[rowA];
            usA = feat4[(size_t)rowA * 16 + c];
        }
        if (rowB < NODES) {
            dvB = dinv[rowB];
            usB = feat4[(size_t)rowB * 16 + c];
        }
        vxA = dvA * (vxA + selfw * __uint_as_float(usA.x << 16));
        vyA = dvA * (vyA + selfw * __uint_as_float(usA.x & 0xffff0000u));
        vzA = dvA * (vzA + selfw * __uint_as_float(usA.y << 16));
        vwA = dvA * (vwA + selfw * __uint_as_float(usA.y & 0xffff0000u));
        vxB = dvB * (vxB + selfw * __uint_as_float(usB.x << 16));
        vyB = dvB * (vyB + selfw * __uint_as_float(usB.x & 0xffff0000u));
        vzB = dvB * (vzB + selfw * __uint_as_float(usB.y << 16));
        vwB = dvB * (vwB + selfw * __uint_as_float(usB.y & 0xffff0000u));
        if (lane < 16) {
            uint2 pA, pB;
            pA.x = (unsigned)tobf(vxA) | ((unsigned)tobf(vyA) << 16);
            pA.y = (unsigned)tobf(vzA) | ((unsigned)tobf(vwA) << 16);
            pB.x = (unsigned)tobf(vxB) | ((unsigned)tobf(vyB) << 16);
            pB.y = (unsigned)tobf(vzB) | ((unsigned)tobf(vwB) << 16);
            *(uint2*)(Vs + (size_t)(wave * 16 + iA) * VSS + c * 4) = pA;
            *(uint2*)(Vs + (size_t)(wave * 16 + iB) * VSS + c * 4) = pB;
        }
    }
    frag8 afr[2];
    int m = lane & 15, q = lane >> 4;
#pragma unroll
    for (int ks = 0; ks < 2; ++ks)
        afr[ks] = *(frag8*)(Vs + (size_t)(wave * 16 + m) * VSS + q * 8 + ks * 32);
#pragma unroll
    for (int nt = 0; nt < 4; ++nt) {
        f32x4 a = {0.f, 0.f, 0.f, 0.f};
#pragma unroll
        for (int ks = 0; ks < 2; ++ks) {
            frag8 bfr = *(frag8*)(Wt + (size_t)(nt * 16 + m) * VSS + q * 8 + ks * 32);
            a = __builtin_amdgcn_mfma_f32_16x16x32_bf16(afr[ks], bfr, a, 0, 0, 0);
        }
        acc[nt] = a;
    }
}

// layer1: gather + MFMA + bias + LN + leaky -> h1s = h1*dinv2 (bf16)
__global__ void __launch_bounds__(256, 2)
gcn1_fused(const uint2* __restrict__ xs4, const int* __restrict__ csr,
           const int* __restrict__ rp, const float* __restrict__ dinv1,
           const float* __restrict__ dinv2, const float* __restrict__ W1,
           const float* __restrict__ b1, const float* __restrict__ lng,
           const float* __restrict__ lnb, bf16* __restrict__ h1s) {
    __shared__ short sm[2 * 64 * VSS];
    short* Vs = sm;
    short* Wt = sm + 64 * VSS;
    int lane = threadIdx.x & 63, wave = threadIdx.x >> 6;
    int rowBase = blockIdx.x * 64;
    f32x4 acc[4];
    gcn_core(xs4, csr, rp, dinv1, 2.0f, W1, Vs, Wt, rowBase, lane, wave, acc);
    int c = lane & 15, q = lane >> 4;
    float bc[4], lg[4], lb[4];
#pragma unroll
    for (int nt = 0; nt < 4; ++nt) {
        bc[nt] = b1[nt * 16 + c];
        lg[nt] = lng[nt * 16 + c];
        lb[nt] = lnb[nt * 16 + c];
    }
#pragma unroll
    for (int r = 0; r < 4; ++r) {
        int grow = rowBase + wave * 16 + q * 4 + r;
        float v0 = acc[0][r] + bc[0], v1 = acc[1][r] + bc[1];
        float v2 = acc[2][r] + bc[2], v3 = acc[3][r] + bc[3];
        float s = v0 + v1 + v2 + v3;
        for (int o = 1; o < 16; o <<= 1) s += __shfl_xor(s, o);
        float mu = s * (1.0f / 64.0f);
        float d0 = v0 - mu, d1 = v1 - mu, d2 = v2 - mu, d3 = v3 - mu;
        float qq = d0 * d0 + d1 * d1 + d2 * d2 + d3 * d3;
        for (int o = 1; o < 16; o <<= 1) qq += __shfl_xor(qq, o);
        float rstd = 1.0f / sqrtf(qq * (1.0f / 64.0f) + 1e-5f);
        if (grow < NODES) {
            float d2v = dinv2[grow];
            bf16* dst = h1s + (size_t)grow * 64 + c;
            dst[0]  = __float2bfloat16(lrelu(d0 * rstd * lg[0] + lb[0]) * d2v);
            dst[16] = __float2bfloat16(lrelu(d1 * rstd * lg[1] + lb[1]) * d2v);
            dst[32] = __float2bfloat16(lrelu(d2 * rstd * lg[2] + lb[2]) * d2v);
            dst[48] = __float2bfloat16(lrelu(d3 * rstd * lg[3] + lb[3]) * d2v);
        }
    }
}

// layer2: gather + MFMA + bias + leaky + run-merged max-pool
__global__ void __launch_bounds__(256, 2)
gcn2_fused(const uint2* __restrict__ h1s4, const int* __restrict__ csr,
           const int* __restrict__ rp, const float* __restrict__ dinv2,
           const float* __restrict__ W2, const float* __restrict__ b2,
           const void* __restrict__ batch, const int* __restrict__ flag,
           unsigned* __restrict__ pooled) {
    __shared__ short sm[2 * 64 * VSS];
    __shared__ int gsh[64];
    short* Vs = sm;
    short* Wt = sm + 64 * VSS;
    int t = threadIdx.x, lane = t & 63, wave = t >> 6;
    int rowBase = blockIdx.x * 64;
    if (t < 64) {
        int row = rowBase + t;
        gsh[t] = (row < NODES) ? idx_at(batch, row, flag[0]) : -1;
    }
    f32x4 acc[4];
    gcn_core(h1s4, csr, rp, dinv2, 1.0f, W2, Vs, Wt, rowBase, lane, wave, acc);
    int c = lane & 15, q = lane >> 4;
    float bc[4];
#pragma unroll
    for (int nt = 0; nt < 4; ++nt) bc[nt] = b2[nt * 16 + c];
    __syncthreads();
    float* P = (float*)sm;  // 64 x 65 fp32 pool buffer
#pragma unroll
    for (int r = 0; r < 4; ++r) {
        int mloc = wave * 16 + q * 4 + r;
#pragma unroll
        for (int nt = 0; nt < 4; ++nt)
            P[(size_t)mloc * 65 + nt * 16 + c] = lrelu(acc[nt][r] + bc[nt]);
    }
    __syncthreads();
    if (wave == 0) {
        float m = P[lane];
        int gc = gsh[0];
        for (int r = 1; r < 64; ++r) {
            int gr = gsh[r];
            float ar = P[(size_t)r * 65 + lane];
            if (gr == gc) {
                m = fmaxf(m, ar);
            } else {
                if ((unsigned)gc < NGRAPH) atomicMax(&pooled[gc * 64 + lane], mapf(m));
                gc = gr;
                m = ar;
            }
        }
        if ((unsigned)gc < NGRAPH) atomicMax(&pooled[gc * 64 + lane], mapf(m));
    }
}

// head: z = pooled@W3+b3; LN; leaky; z@W4+b4; softmax. One block per graph.
__global__ void head_kernel(const unsigned* __restrict__ pooled, const float* __restrict__ W3,
                            const float* __restrict__ b3, const float* __restrict__ g2,
                            const float* __restrict__ be2, const float* __restrict__ W4,
                            const float* __restrict__ b4, float* __restrict__ out) {
    __shared__ float prow[64];
    __shared__ float z[768];
    __shared__ float rs[4], rss[4];
    __shared__ float mu_s, rstd_s;
    __shared__ float red[10];
    int t = threadIdx.x, gI = blockIdx.x;
    if (t < 64) prow[t] = unmapf(pooled[gI * 64 + t]);
    __syncthreads();
    for (int c = t; c < 768; c += 256) {
        float acc = b3[c];
#pragma unroll 16
        for (int k = 0; k < 64; ++k) acc += prow[k] * W3[k * 768 + c];
        z[c] = acc;
    }
    __syncthreads();
    float s = 0.0f, ss = 0.0f;
    for (int c = t; c < 768; c += 256) {
        float v = z[c];
        s += v;
        ss += v * v;
    }
    for (int o = 32; o; o >>= 1) {
        s += __shfl_xor(s, o);
        ss += __shfl_xor(ss, o);
    }
    if ((t & 63) == 0) { rs[t >> 6] = s; rss[t >> 6] = ss; }
    __syncthreads();
    if (t == 0) {
        float S = rs[0] + rs[1] + rs[2] + rs[3];
        float SS = rss[0] + rss[1] + rss[2] + rss[3];
        float mu = S * (1.0f / 768.0f);
        float var = SS * (1.0f / 768.0f) - mu * mu;
        mu_s = mu;
        rstd_s = 1.0f / sqrtf(fmaxf(var, 0.0f) + 1e-5f);
    }
    __syncthreads();
    for (int c = t; c < 768; c += 256) {
        float y = (z[c] - mu_s) * rstd_s * g2[c] + be2[c];
        z[c] = lrelu(y);
    }
    if (t < 10) red[t] = 0.0f;
    __syncthreads();
    float p[10];
#pragma unroll
    for (int c = 0; c < 10; ++c) p[c] = 0.0f;
    for (int k = t; k < 768; k += 256) {
        float zv = z[k];
#pragma unroll
        for (int c = 0; c < 10; ++c) p[c] += zv * W4[k * 10 + c];
    }
#pragma unroll
    for (int c = 0; c < 10; ++c) atomicAdd(&red[c], p[c]);
    __syncthreads();
    if (t == 0) {
        float l[10], m = -1e30f;
#pragma unroll
        for (int c = 0; c < 10; ++c) {
            l[c] = red[c] + b4[c];
            m = fmaxf(m, l[c]);
        }
        float sum = 0.0f;
#pragma unroll
        for (int c = 0; c < 10; ++c) {
            l[c] = expf(l[c] - m);
            sum += l[c];
        }
        float inv = 1.0f / sum;
#pragma unroll
        for (int c = 0; c < 10; ++c) out[gI * 10 + c] = l[c] * inv;
    }
}

extern "C" void kernel_launch(void* const* d_in, const int* in_sizes, int n_in,
                              void* d_out, int out_size, void* d_ws, size_t ws_size,
                              hipStream_t stream) {
    const size_t REQUIRED = (size_t)NODES * 64 * 2 * 2    // xs + h1s (staging aliases h1s)
                          + (size_t)EDGES * 4             // csr_src
                          + (size_t)(NODES + 1) * 4       // row_ptr
                          + (size_t)NODES * 4 * 2         // dinv1, dinv2
                          + (size_t)NBINS * 4             // binCursor
                          + (size_t)NGRAPH * 64 * 4       // pooled
                          + 16;                           // flag
    if (ws_size < REQUIRED) {
        sentinel_kernel<<<20, 256, 0, stream>>>((float*)d_out, 64.0f);
        return;
    }

    const float* x = (const float*)d_in[0];
    const int* eiw = (const int*)d_in[1];
    const void* batch = d_in[2];
    const float* W1 = (const float*)d_in[3];
    const float* b1 = (const float*)d_in[4];
    const float* lng = (const float*)d_in[5];
    const float* lnb = (const float*)d_in[6];
    const float* W2 = (const float*)d_in[7];
    const float* b2 = (const float*)d_in[8];
    const float* W3 = (const float*)d_in[9];
    const float* b3 = (const float*)d_in[10];
    const float* g2 = (const float*)d_in[11];
    const float* be2 = (const float*)d_in[12];
    const float* W4 = (const float*)d_in[13];
    const float* b4 = (const float*)d_in[14];

    bf16* xs = (bf16*)d_ws;                               // N*64 bf16
    bf16* h1s = xs + (size_t)NODES * 64;                  // N*64 bf16 (12.8 MB)
    unsigned* staging = (unsigned*)h1s;                   // NBINS*BINCAP*4 = 9.63 MB alias
    int* csr_src = (int*)(h1s + (size_t)NODES * 64);      // E
    int* row_ptr = csr_src + EDGES;                       // N+1
    float* dinv1 = (float*)(row_ptr + NODES + 1);         // N
    float* dinv2 = dinv1 + NODES;                         // N
    int* binCursor = (int*)(dinv2 + NODES);               // NBINS
    unsigned* pooled = (unsigned*)(binCursor + NBINS);    // G*64
    int* flag = (int*)(pooled + NGRAPH * 64);             // 1

    // pooled sentinel = 0 (0x00000000 < mapf(v) for every real float v)
    hipMemsetAsync(binCursor, 0, (size_t)NBINS * 4, stream);
    hipMemsetAsync(pooled, 0, (size_t)NGRAPH * 64 * 4, stream);

    // staging build (single edge-pass kernel; fixed-capacity bin slots)
    binPlace<<<NCHUNKS, 256, 0, stream>>>(eiw, flag, binCursor, staging);
    csr_finalize<<<NBINS, 256, 0, stream>>>(staging, binCursor, row_ptr, dinv1, dinv2,
                                            csr_src);
    prescale_x<<<(NODES * 16 + 255) / 256, 256, 0, stream>>>(x, dinv1, xs);

    // fused layers: 64 rows/block (4 waves x 16 rows), dual-chain gather + MFMA
    gcn1_fused<<<(NODES + 63) / 64, 256, 0, stream>>>((const uint2*)xs, csr_src, row_ptr,
                                                      dinv1, dinv2, W1, b1, lng, lnb, h1s);
    gcn2_fused<<<(NODES + 63) / 64, 256, 0, stream>>>((const uint2*)h1s, csr_src, row_ptr,
                                                      dinv2, W2, b2, batch, flag, pooled);

    // head
    head_kernel<<<NGRAPH, 256, 0, stream>>>(pooled, W3, b3, g2, be2, W4, b4, (float*)d_out);
}